// Round 4
// baseline (758.901 us; speedup 1.0000x reference)
//
#include <hip/hip_runtime.h>
#include <hip/hip_bf16.h>
#include <hip/hip_fp16.h>

// Problem dims (hard-coded): B=8, S=4096, DIM=1024, M=1024
// Algebraic restructure: attn = x @ (mem·W)^T + (mem·b); softmax; out = probs @ mem
// Round 3: round-2 (__builtin_nontemporal_* on all streaming traffic) with the
// compile fix: nontemporal loads use clang ext-vector f32x4, not HIP float4.
#define KDIM 1024

typedef __attribute__((ext_vector_type(8))) __bf16    bf16x8;
typedef __attribute__((ext_vector_type(4))) __bf16    bf16x4;
typedef __attribute__((ext_vector_type(8))) _Float16  half8;
typedef __attribute__((ext_vector_type(4))) _Float16  half4v;
typedef __attribute__((ext_vector_type(4))) float     f32x4;

// async global->LDS, 16B per lane. LDS base must be wave-uniform; HW adds lane*16.
__device__ __forceinline__ void g2l16(const void* g, void* l) {
  __builtin_amdgcn_global_load_lds(
      (const __attribute__((address_space(1))) unsigned int*)g,
      (__attribute__((address_space(3))) unsigned int*)l, 16, 0, 0);
}

__device__ __forceinline__ void split2(float v, __bf16& h, __bf16& l) {
  h = (__bf16)v;
  l = (__bf16)(v - (float)h);
}

// ---------------------------------------------------------------------------
// split mem into bf16 hi/lo (row-major [m][e], already B^T/A layout for P-GEMM)
__global__ __launch_bounds__(256) void split_mem(
    const float* __restrict__ mem, __bf16* __restrict__ Mh, __bf16* __restrict__ Ml) {
  int i = blockIdx.x * 256 + threadIdx.x;   // 1M threads
  __bf16 h, l;
  split2(mem[i], h, l);
  Mh[i] = h; Ml[i] = l;
}

// transpose W [e][d] -> Wt [d][e], split to bf16 hi/lo (B^T layout for P-GEMM)
__global__ __launch_bounds__(256) void transpose_split_W(
    const float* __restrict__ W, __bf16* __restrict__ Wth, __bf16* __restrict__ Wtl) {
  __shared__ float tl[32][33];
  int bx = blockIdx.x, by = blockIdx.y;
  int tx = threadIdx.x, ty = threadIdx.y;   // (32, 8)
#pragma unroll
  for (int j = 0; j < 4; ++j)
    tl[ty + 8 * j][tx] = W[(by * 32 + ty + 8 * j) * 1024 + bx * 32 + tx];
  __syncthreads();
#pragma unroll
  for (int j = 0; j < 4; ++j) {
    float v = tl[tx][ty + 8 * j];
    __bf16 h, l;
    split2(v, h, l);
    const int idx = (bx * 32 + ty + 8 * j) * 1024 + by * 32 + tx;
    Wth[idx] = h; Wtl[idx] = l;
  }
}

// transpose mem [m][d] -> memT fp16 [d][m] (B^T layout for context GEMM)
__global__ __launch_bounds__(256) void transpose_mem(
    const float* __restrict__ mem, _Float16* __restrict__ memT) {
  __shared__ float tl[32][33];
  int bx = blockIdx.x, by = blockIdx.y;
  int tx = threadIdx.x, ty = threadIdx.y;   // (32, 8)
#pragma unroll
  for (int j = 0; j < 4; ++j)
    tl[ty + 8 * j][tx] = mem[(by * 32 + ty + 8 * j) * 1024 + bx * 32 + tx];
  __syncthreads();
#pragma unroll
  for (int j = 0; j < 4; ++j)
    memT[(bx * 32 + ty + 8 * j) * 1024 + by * 32 + tx] =
        (_Float16)tl[tx][ty + 8 * j];
}

// c[m] = sum_e b[e] * mem[m][e]  (fp32). One wave per row.
__global__ __launch_bounds__(256) void bias_c(
    const float* __restrict__ b, const float* __restrict__ mem,
    float* __restrict__ c) {
  const int wave = threadIdx.x >> 6, lane = threadIdx.x & 63;
  const int row = blockIdx.x * 4 + wave;
  float s = 0.f;
#pragma unroll
  for (int j = 0; j < 16; ++j) {
    const int e = lane + 64 * j;
    s += b[e] * mem[row * 1024 + e];
  }
#pragma unroll
  for (int off = 32; off; off >>= 1) s += __shfl_xor(s, off);
  if (lane == 0) c[row] = s;
}

// ---------------------------------------------------------------------------
// Split-bf16 compensated GEMM, C = A @ B^T (3 MFMA products: hh + hl + lh).
// 128x128 tile, BK=32, 32 KB LDS, 4 waves (known-good m97-ish structure).
// MODE 0 (P-GEMM): A pre-split bf16 hi/lo; epilogue writes C as bf16 hi/lo.
// MODE 1 (big GEMM): A = x fp32 (split inline during staging, nt loads);
//                    epilogue adds bias[col] and writes fp32 via nt stores.
template <int MODE>
__global__ __launch_bounds__(256) void gemm_split(
    const float* __restrict__ X,
    const __bf16* __restrict__ Agh, const __bf16* __restrict__ Agl,
    const __bf16* __restrict__ Bgh, const __bf16* __restrict__ Bgl,
    const float* __restrict__ bias,
    __bf16* __restrict__ Oh, __bf16* __restrict__ Ol,
    float* __restrict__ Of) {
  __shared__ __attribute__((aligned(16))) __bf16 Ah[128 * 32];
  __shared__ __attribute__((aligned(16))) __bf16 Al[128 * 32];
  __shared__ __attribute__((aligned(16))) __bf16 Bh[128 * 32];
  __shared__ __attribute__((aligned(16))) __bf16 Bl[128 * 32];

  const int t = threadIdx.x;
  const int wave = t >> 6;
  const int lane = t & 63;
  const int wm = wave & 1, wn = wave >> 1;
  const int tileM = blockIdx.y * 128;
  const int tileN = blockIdx.x * 128;

  f32x4 acc[4][4] = {};

  const int rS = lane >> 2;        // row within 16-row staging group
  const int cS = (lane & 3) * 8;   // k element offset within BK=32

  for (int kt = 0; kt < KDIM / 32; ++kt) {
    const int k0 = kt * 32;
    __syncthreads();
    // --- stage B^T tile (rows tileN..tileN+127, k0..k0+31), hi+lo
#pragma unroll
    for (int i = 0; i < 2; ++i) {
      const int rb = i * 64 + wave * 16;  // wave-uniform LDS row base
      const int gro = (tileN + rb + rS) * KDIM + k0 + cS;
      g2l16(Bgh + gro, &Bh[rb * 32]);
      g2l16(Bgl + gro, &Bl[rb * 32]);
    }
    if constexpr (MODE == 0) {
#pragma unroll
      for (int i = 0; i < 2; ++i) {
        const int rb = i * 64 + wave * 16;
        const int gro = (tileM + rb + rS) * KDIM + k0 + cS;
        g2l16(Agh + gro, &Ah[rb * 32]);
        g2l16(Agl + gro, &Al[rb * 32]);
      }
    } else {
      // inline fp32 -> bf16 hi/lo split of x during staging (nt: x is
      // streamed once; keep it out of L2 so P-split tiles stay resident)
#pragma unroll
      for (int i = 0; i < 4; ++i) {
        const int idx = i * 256 + t;
        const int row = idx >> 3;
        const int c4 = (idx & 7) * 4;
        const f32x4 v = __builtin_nontemporal_load(
            (const f32x4*)(X + (size_t)(tileM + row) * KDIM + k0 + c4));
        bf16x4 h, l;
#pragma unroll
        for (int j = 0; j < 4; ++j) {
          const float vj = v[j];
          __bf16 hh = (__bf16)vj;
          h[j] = hh;
          l[j] = (__bf16)(vj - (float)hh);
        }
        *(bf16x4*)(&Ah[row * 32 + c4]) = h;
        *(bf16x4*)(&Al[row * 32 + c4]) = l;
      }
    }
    __syncthreads();

    const int fr = lane & 15;
    const int fk = (lane >> 4) * 8;
    bf16x8 afh[4], afl[4], bfh[4], bfl[4];
#pragma unroll
    for (int mf = 0; mf < 4; ++mf) {
      const int r = wm * 64 + mf * 16 + fr;
      afh[mf] = *(const bf16x8*)(&Ah[r * 32 + fk]);
      afl[mf] = *(const bf16x8*)(&Al[r * 32 + fk]);
    }
#pragma unroll
    for (int nf = 0; nf < 4; ++nf) {
      const int r = wn * 64 + nf * 16 + fr;
      bfh[nf] = *(const bf16x8*)(&Bh[r * 32 + fk]);
      bfl[nf] = *(const bf16x8*)(&Bl[r * 32 + fk]);
    }
#pragma unroll
    for (int mf = 0; mf < 4; ++mf)
#pragma unroll
      for (int nf = 0; nf < 4; ++nf) {
        acc[mf][nf] = __builtin_amdgcn_mfma_f32_16x16x32_bf16(afh[mf], bfh[nf], acc[mf][nf], 0, 0, 0);
        acc[mf][nf] = __builtin_amdgcn_mfma_f32_16x16x32_bf16(afh[mf], bfl[nf], acc[mf][nf], 0, 0, 0);
        acc[mf][nf] = __builtin_amdgcn_mfma_f32_16x16x32_bf16(afl[mf], bfh[nf], acc[mf][nf], 0, 0, 0);
      }
  }

  // --- epilogue. C/D layout: col = lane&15, row = (lane>>4)*4 + reg
  const int er = (lane >> 4) * 4;
  const int ec = lane & 15;
#pragma unroll
  for (int nf = 0; nf < 4; ++nf) {
    const int col = tileN + wn * 64 + nf * 16 + ec;
    float bv = 0.0f;
    if constexpr (MODE == 1) bv = bias[col];
#pragma unroll
    for (int mf = 0; mf < 4; ++mf) {
#pragma unroll
      for (int r = 0; r < 4; ++r) {
        const int row = tileM + wm * 64 + mf * 16 + er + r;
        const size_t idx = (size_t)row * KDIM + col;
        float v = acc[mf][nf][r];
        if constexpr (MODE == 0) {
          __bf16 h = (__bf16)v;
          Oh[idx] = h;
          Ol[idx] = (__bf16)(v - (float)h);
        } else {
          __builtin_nontemporal_store(v + bv, &Of[idx]);  // attn: streamed out
        }
      }
    }
  }
}

// ---------------------------------------------------------------------------
// Fused softmax + context GEMM (structure identical to round 1; the only
// change is nt hints on the streaming attn reads and out writes so memT
// stays L2-resident for the B-operand loads in the K-loop).
__global__ __launch_bounds__(512, 2) void fused_softmax_ctx(
    const float* __restrict__ attn, const _Float16* __restrict__ memT,
    float* __restrict__ out) {
  __shared__ __attribute__((aligned(16))) _Float16 P[32 * 1024];  // 64 KB

  const int t = threadIdx.x;
  const int wave = t >> 6, lane = t & 63;
  const int riw = lane >> 4;       // row within wave's 4-row group
  const int cg = lane & 15;        // col group (16 threads per row)
  const int row = wave * 4 + riw;  // 0..31 (softmax phase row ownership)
  const size_t grow0 = (size_t)blockIdx.x * 32;

  // GEMM-phase lane geometry (needed early for the b0 prefetch)
  const int colbase = wave * 128;
  const int fr = lane & 15;
  const int fko = (lane >> 4) * 8;   // k element offset within 32
  const _Float16* bbase = memT + (size_t)(colbase + fr) * 1024 + fko;

  // --- 1. load this row's 1024 attn values across its 16 threads (64 each)
  //        (nontemporal: attn is read exactly once; don't evict memT)
  f32x4 v[16];
  {
    const f32x4* arow = (const f32x4*)(attn + (grow0 + row) * 1024);
#pragma unroll
    for (int j = 0; j < 16; ++j)
      v[j] = __builtin_nontemporal_load(arow + cg + j * 16);
  }

  // prefetch B-frags for kt=0 now; the softmax math below waits on the attn
  // loads with a counted vmcnt, so these stay in flight for free.
  half8 b0[8], b1[8];
#pragma unroll
  for (int nf = 0; nf < 8; ++nf)
    b0[nf] = *(const half8*)(bbase + nf * 16384);

  // --- 2a. row max (reduce over the 16-lane row group)
  float m = -1e30f;
#pragma unroll
  for (int j = 0; j < 16; ++j)
    m = fmaxf(m, fmaxf(fmaxf(v[j].x, v[j].y), fmaxf(v[j].z, v[j].w)));
#pragma unroll
  for (int off = 1; off < 16; off <<= 1) m = fmaxf(m, __shfl_xor(m, off));

  // --- 2b. exp in place + row sum
  float s = 0.f;
#pragma unroll
  for (int j = 0; j < 16; ++j) {
    v[j].x = expf(v[j].x - m);
    v[j].y = expf(v[j].y - m);
    v[j].z = expf(v[j].z - m);
    v[j].w = expf(v[j].w - m);
    s += (v[j].x + v[j].y) + (v[j].z + v[j].w);
  }
#pragma unroll
  for (int off = 1; off < 16; off <<= 1) s += __shfl_xor(s, off);
  const float inv = 1.0f / s;

  // --- 3. write normalized fp16 probs to LDS, XOR-swizzled by row
  {
    const int swz = (row & 7) << 4;
    char* rbase = (char*)P + row * 2048;
#pragma unroll
    for (int j = 0; j < 16; ++j) {
      half4v o;
      o[0] = (_Float16)(v[j].x * inv);
      o[1] = (_Float16)(v[j].y * inv);
      o[2] = (_Float16)(v[j].z * inv);
      o[3] = (_Float16)(v[j].w * inv);
      const int byteoff = (cg * 8 + j * 128) ^ swz;   // 8B-aligned, bijective
      *(half4v*)(rbase + byteoff) = o;
    }
  }

  // prefetch B-frags for kt=1 before the barrier
#pragma unroll
  for (int nf = 0; nf < 8; ++nf)
    b1[nf] = *(const half8*)(bbase + nf * 16384 + 32);

  __syncthreads();

  // --- 4. context GEMM: out[32 rows][wave's 128 cols] = P @ memT^T
  // Depth-2 pipeline: step A consumes b0 (kt), step B consumes b1 (kt+1);
  // each step re-issues its buffer's loads for kt+2 after the MFMAs read it.
  f32x4 acc[2][8] = {};

  for (int kt = 0; kt < 32; kt += 2) {
    // ---- step A: kt, uses b0
    {
      half8 a[2];
#pragma unroll
      for (int mf = 0; mf < 2; ++mf) {
        const int ar = mf * 16 + fr;
        const int kbyte = ((kt * 32 + fko) * 2) ^ ((ar & 7) << 4);
        a[mf] = *(const half8*)((const char*)P + ar * 2048 + kbyte);
      }
#pragma unroll
      for (int mf = 0; mf < 2; ++mf)
#pragma unroll
        for (int nf = 0; nf < 8; ++nf)
          acc[mf][nf] = __builtin_amdgcn_mfma_f32_16x16x32_f16(a[mf], b0[nf], acc[mf][nf], 0, 0, 0);
      if (kt + 2 < 32) {
#pragma unroll
        for (int nf = 0; nf < 8; ++nf)
          b0[nf] = *(const half8*)(bbase + nf * 16384 + (kt + 2) * 32);
      }
    }
    // ---- step B: kt+1, uses b1
    {
      half8 a[2];
#pragma unroll
      for (int mf = 0; mf < 2; ++mf) {
        const int ar = mf * 16 + fr;
        const int kbyte = (((kt + 1) * 32 + fko) * 2) ^ ((ar & 7) << 4);
        a[mf] = *(const half8*)((const char*)P + ar * 2048 + kbyte);
      }
#pragma unroll
      for (int mf = 0; mf < 2; ++mf)
#pragma unroll
        for (int nf = 0; nf < 8; ++nf)
          acc[mf][nf] = __builtin_amdgcn_mfma_f32_16x16x32_f16(a[mf], b1[nf], acc[mf][nf], 0, 0, 0);
      if (kt + 3 < 32) {
#pragma unroll
        for (int nf = 0; nf < 8; ++nf)
          b1[nf] = *(const half8*)(bbase + nf * 16384 + (kt + 3) * 32);
      }
    }
  }

  // --- epilogue. C/D layout: col = lane&15, row = (lane>>4)*4 + reg
  //     (nontemporal: out is write-once streaming)
  const int er = (lane >> 4) * 4;
  const int ec = lane & 15;
#pragma unroll
  for (int mf = 0; mf < 2; ++mf)
#pragma unroll
    for (int nf = 0; nf < 8; ++nf) {
      const int col = colbase + nf * 16 + ec;
#pragma unroll
      for (int r = 0; r < 4; ++r)
        __builtin_nontemporal_store(
            acc[mf][nf][r], &out[(grow0 + mf * 16 + er + r) * 1024 + col]);
    }
}

// ---------------------------------------------------------------------------
extern "C" void kernel_launch(void* const* d_in, const int* in_sizes, int n_in,
                              void* d_out, int out_size, void* d_ws, size_t ws_size,
                              hipStream_t stream) {
  const float* x   = (const float*)d_in[0];   // [32768][1024]
  const float* W   = (const float*)d_in[1];   // [1024][1024]  (out=e, in=d)
  const float* b   = (const float*)d_in[2];   // [1024]
  const float* mem = (const float*)d_in[3];   // [1024][1024]  (m, e)
  float* out = (float*)d_out;

  char* ws = (char*)d_ws;
  const size_t MB = 1024 * 1024;
  float*    attn  = (float*)(ws);              // 128 MB
  __bf16*   Mh    = (__bf16*)(ws + 192 * MB);  // 2 MB
  __bf16*   Ml    = (__bf16*)(ws + 194 * MB);  // 2 MB
  __bf16*   Wth   = (__bf16*)(ws + 196 * MB);  // 2 MB
  __bf16*   Wtl   = (__bf16*)(ws + 198 * MB);  // 2 MB
  __bf16*   Ph    = (__bf16*)(ws + 200 * MB);  // 2 MB
  __bf16*   Pl    = (__bf16*)(ws + 202 * MB);  // 2 MB
  _Float16* memT  = (_Float16*)(ws + 204 * MB);// 2 MB
  float*    cvec  = (float*)(ws + 206 * MB);   // 4 KB

  // preps (all tiny)
  split_mem<<<4096, 256, 0, stream>>>(mem, Mh, Ml);
  transpose_split_W<<<dim3(32, 32), dim3(32, 8), 0, stream>>>(W, Wth, Wtl);
  transpose_mem<<<dim3(32, 32), dim3(32, 8), 0, stream>>>(mem, memT);
  bias_c<<<256, 256, 0, stream>>>(b, mem, cvec);

  // P = mem @ W  (P[m][d] = sum_e mem[m][e] W[e][d]); split-bf16, out split bf16
  gemm_split<0><<<dim3(8, 8), 256, 0, stream>>>(
      nullptr, Mh, Ml, Wth, Wtl, nullptr, Ph, Pl, nullptr);

  // attn = x @ P^T + c  (split-bf16 via inline x split; fp32 logits)
  gemm_split<1><<<dim3(8, 256), 256, 0, stream>>>(
      x, nullptr, nullptr, Ph, Pl, cvec, nullptr, nullptr, attn);

  // fused softmax + context = probs @ mem  (depth-2 reg pipeline on memT)
  fused_softmax_ctx<<<1024, 512, 0, stream>>>(attn, memT, out);
}

// Round 5
// 600.044 us; speedup vs baseline: 1.2647x; 1.2647x over previous
//
#include <hip/hip_runtime.h>
#include <hip/hip_bf16.h>
#include <hip/hip_fp16.h>

// Problem dims (hard-coded): B=8, S=4096, DIM=1024, M=1024
// Algebraic restructure: attn = x @ (mem·W)^T + (mem·b); softmax; out = probs @ mem
// Round 5: (a) revert all nontemporal hints (r4: regressed, WRITE +40%);
// (b) B operand of the fused context GEMM pre-packed into MFMA-fragment order
//     (memTb) so every B-load is one contiguous 1-KB wave read instead of 16
//     strided 64-B segments; (c) XCD-aware bijective block swizzle in
//     gemm_split so blocks sharing an x-band run on one XCD (L2 reuse).
#define KDIM 1024

typedef __attribute__((ext_vector_type(8))) __bf16    bf16x8;
typedef __attribute__((ext_vector_type(4))) __bf16    bf16x4;
typedef __attribute__((ext_vector_type(8))) _Float16  half8;
typedef __attribute__((ext_vector_type(4))) _Float16  half4v;
typedef __attribute__((ext_vector_type(4))) float     f32x4;

// async global->LDS, 16B per lane. LDS base must be wave-uniform; HW adds lane*16.
__device__ __forceinline__ void g2l16(const void* g, void* l) {
  __builtin_amdgcn_global_load_lds(
      (const __attribute__((address_space(1))) unsigned int*)g,
      (__attribute__((address_space(3))) unsigned int*)l, 16, 0, 0);
}

__device__ __forceinline__ void split2(float v, __bf16& h, __bf16& l) {
  h = (__bf16)v;
  l = (__bf16)(v - (float)h);
}

// ---------------------------------------------------------------------------
// split mem into bf16 hi/lo (row-major [m][e], already B^T/A layout for P-GEMM)
__global__ __launch_bounds__(256) void split_mem(
    const float* __restrict__ mem, __bf16* __restrict__ Mh, __bf16* __restrict__ Ml) {
  int i = blockIdx.x * 256 + threadIdx.x;   // 1M threads
  __bf16 h, l;
  split2(mem[i], h, l);
  Mh[i] = h; Ml[i] = l;
}

// transpose W [e][d] -> Wt [d][e], split to bf16 hi/lo (B^T layout for P-GEMM)
__global__ __launch_bounds__(256) void transpose_split_W(
    const float* __restrict__ W, __bf16* __restrict__ Wth, __bf16* __restrict__ Wtl) {
  __shared__ float tl[32][33];
  int bx = blockIdx.x, by = blockIdx.y;
  int tx = threadIdx.x, ty = threadIdx.y;   // (32, 8)
#pragma unroll
  for (int j = 0; j < 4; ++j)
    tl[ty + 8 * j][tx] = W[(by * 32 + ty + 8 * j) * 1024 + bx * 32 + tx];
  __syncthreads();
#pragma unroll
  for (int j = 0; j < 4; ++j) {
    float v = tl[tx][ty + 8 * j];
    __bf16 h, l;
    split2(v, h, l);
    const int idx = (bx * 32 + ty + 8 * j) * 1024 + by * 32 + tx;
    Wth[idx] = h; Wtl[idx] = l;
  }
}

// mem [m][e] fp32 -> memTb fp16: context-GEMM B operand packed in MFMA
// B-fragment lane order. Fragment f = nt*32 + kt (nt = 16-col group of the
// output d-dim, kt = 32-wide k group of the m-dim); entry (lane l, j):
//   value = (fp16) mem[kt*32 + (l>>4)*8 + j][nt*16 + (l&15)]
//   byte offset = f*1024 + l*16 + j*2
// A wave's B-load in the fused kernel is then one contiguous 1-KB read.
__global__ __launch_bounds__(256) void build_memTb(
    const float* __restrict__ mem, _Float16* __restrict__ memTb) {
  const int id = blockIdx.x * 256 + threadIdx.x;   // 131072 threads
  const int l  = id & 63;
  const int f  = id >> 6;        // 0..2047
  const int kt = f & 31;
  const int nt = f >> 5;
  const int n  = nt * 16 + (l & 15);
  const int k0 = kt * 32 + (l >> 4) * 8;
  half8 o;
#pragma unroll
  for (int j = 0; j < 8; ++j)
    o[j] = (_Float16)mem[(size_t)(k0 + j) * 1024 + n];
  *(half8*)(memTb + (size_t)id * 8) = o;
}

// c[m] = sum_e b[e] * mem[m][e]  (fp32). One wave per row.
__global__ __launch_bounds__(256) void bias_c(
    const float* __restrict__ b, const float* __restrict__ mem,
    float* __restrict__ c) {
  const int wave = threadIdx.x >> 6, lane = threadIdx.x & 63;
  const int row = blockIdx.x * 4 + wave;
  float s = 0.f;
#pragma unroll
  for (int j = 0; j < 16; ++j) {
    const int e = lane + 64 * j;
    s += b[e] * mem[row * 1024 + e];
  }
#pragma unroll
  for (int off = 32; off; off >>= 1) s += __shfl_xor(s, off);
  if (lane == 0) c[row] = s;
}

// ---------------------------------------------------------------------------
// Split-bf16 compensated GEMM, C = A @ B^T (3 MFMA products: hh + hl + lh).
// 128x128 tile, BK=32, 32 KB LDS, 4 waves (known-good m97-ish structure).
// MODE 0 (P-GEMM): A pre-split bf16 hi/lo; epilogue writes C as bf16 hi/lo.
// MODE 1 (big GEMM): A = x fp32 (split inline during staging); epilogue adds
//                    bias[col] and writes fp32.
// XCD swizzle: blocks sharing a tileM x-band (consecutive flat ids) are
// remapped so they dispatch consecutively onto ONE XCD -> x-tile fetched once
// per XCD L2 instead of 8x.
template <int MODE>
__global__ __launch_bounds__(256) void gemm_split(
    const float* __restrict__ X,
    const __bf16* __restrict__ Agh, const __bf16* __restrict__ Agl,
    const __bf16* __restrict__ Bgh, const __bf16* __restrict__ Bgl,
    const float* __restrict__ bias,
    __bf16* __restrict__ Oh, __bf16* __restrict__ Ol,
    float* __restrict__ Of) {
  __shared__ __attribute__((aligned(16))) __bf16 Ah[128 * 32];
  __shared__ __attribute__((aligned(16))) __bf16 Al[128 * 32];
  __shared__ __attribute__((aligned(16))) __bf16 Bh[128 * 32];
  __shared__ __attribute__((aligned(16))) __bf16 Bl[128 * 32];

  const int t = threadIdx.x;
  const int wave = t >> 6;
  const int lane = t & 63;
  const int wm = wave & 1, wn = wave >> 1;

  // XCD-aware bijective remap (hardware round-robins linear id across 8 XCDs)
  const int nwg = gridDim.x * gridDim.y;
  int flat = blockIdx.y * gridDim.x + blockIdx.x;
  if ((nwg & 7) == 0) {
    const int cpx = nwg >> 3;
    flat = (flat & 7) * cpx + (flat >> 3);
  }
  const int tileN = (flat % gridDim.x) * 128;
  const int tileM = (flat / gridDim.x) * 128;

  f32x4 acc[4][4] = {};

  const int rS = lane >> 2;        // row within 16-row staging group
  const int cS = (lane & 3) * 8;   // k element offset within BK=32

  for (int kt = 0; kt < KDIM / 32; ++kt) {
    const int k0 = kt * 32;
    __syncthreads();
    // --- stage B^T tile (rows tileN..tileN+127, k0..k0+31), hi+lo
#pragma unroll
    for (int i = 0; i < 2; ++i) {
      const int rb = i * 64 + wave * 16;  // wave-uniform LDS row base
      const int gro = (tileN + rb + rS) * KDIM + k0 + cS;
      g2l16(Bgh + gro, &Bh[rb * 32]);
      g2l16(Bgl + gro, &Bl[rb * 32]);
    }
    if constexpr (MODE == 0) {
#pragma unroll
      for (int i = 0; i < 2; ++i) {
        const int rb = i * 64 + wave * 16;
        const int gro = (tileM + rb + rS) * KDIM + k0 + cS;
        g2l16(Agh + gro, &Ah[rb * 32]);
        g2l16(Agl + gro, &Al[rb * 32]);
      }
    } else {
      // inline fp32 -> bf16 hi/lo split of x during staging
#pragma unroll
      for (int i = 0; i < 4; ++i) {
        const int idx = i * 256 + t;
        const int row = idx >> 3;
        const int c4 = (idx & 7) * 4;
        const f32x4 v = *(const f32x4*)(X + (size_t)(tileM + row) * KDIM + k0 + c4);
        bf16x4 h, l;
#pragma unroll
        for (int j = 0; j < 4; ++j) {
          const float vj = v[j];
          __bf16 hh = (__bf16)vj;
          h[j] = hh;
          l[j] = (__bf16)(vj - (float)hh);
        }
        *(bf16x4*)(&Ah[row * 32 + c4]) = h;
        *(bf16x4*)(&Al[row * 32 + c4]) = l;
      }
    }
    __syncthreads();

    const int fr = lane & 15;
    const int fk = (lane >> 4) * 8;
    bf16x8 afh[4], afl[4], bfh[4], bfl[4];
#pragma unroll
    for (int mf = 0; mf < 4; ++mf) {
      const int r = wm * 64 + mf * 16 + fr;
      afh[mf] = *(const bf16x8*)(&Ah[r * 32 + fk]);
      afl[mf] = *(const bf16x8*)(&Al[r * 32 + fk]);
    }
#pragma unroll
    for (int nf = 0; nf < 4; ++nf) {
      const int r = wn * 64 + nf * 16 + fr;
      bfh[nf] = *(const bf16x8*)(&Bh[r * 32 + fk]);
      bfl[nf] = *(const bf16x8*)(&Bl[r * 32 + fk]);
    }
#pragma unroll
    for (int mf = 0; mf < 4; ++mf)
#pragma unroll
      for (int nf = 0; nf < 4; ++nf) {
        acc[mf][nf] = __builtin_amdgcn_mfma_f32_16x16x32_bf16(afh[mf], bfh[nf], acc[mf][nf], 0, 0, 0);
        acc[mf][nf] = __builtin_amdgcn_mfma_f32_16x16x32_bf16(afh[mf], bfl[nf], acc[mf][nf], 0, 0, 0);
        acc[mf][nf] = __builtin_amdgcn_mfma_f32_16x16x32_bf16(afl[mf], bfh[nf], acc[mf][nf], 0, 0, 0);
      }
  }

  // --- epilogue. C/D layout: col = lane&15, row = (lane>>4)*4 + reg
  const int er = (lane >> 4) * 4;
  const int ec = lane & 15;
#pragma unroll
  for (int nf = 0; nf < 4; ++nf) {
    const int col = tileN + wn * 64 + nf * 16 + ec;
    float bv = 0.0f;
    if constexpr (MODE == 1) bv = bias[col];
#pragma unroll
    for (int mf = 0; mf < 4; ++mf) {
#pragma unroll
      for (int r = 0; r < 4; ++r) {
        const int row = tileM + wm * 64 + mf * 16 + er + r;
        const size_t idx = (size_t)row * KDIM + col;
        float v = acc[mf][nf][r];
        if constexpr (MODE == 0) {
          __bf16 h = (__bf16)v;
          Oh[idx] = h;
          Ol[idx] = (__bf16)(v - (float)h);
        } else {
          Of[idx] = v + bv;
        }
      }
    }
  }
}

// ---------------------------------------------------------------------------
// Fused softmax + context GEMM (round-1 structure; B operand now loaded from
// the fragment-packed memTb: one contiguous 1-KB wave read per fragment
// instead of 16 x 64-B strided segments).
__global__ __launch_bounds__(512, 2) void fused_softmax_ctx(
    const float* __restrict__ attn, const _Float16* __restrict__ memTb,
    float* __restrict__ out) {
  __shared__ __attribute__((aligned(16))) _Float16 P[32 * 1024];  // 64 KB

  const int t = threadIdx.x;
  const int wave = t >> 6, lane = t & 63;
  const int riw = lane >> 4;       // row within wave's 4-row group
  const int cg = lane & 15;        // col group (16 threads per row)
  const int row = wave * 4 + riw;  // 0..31 (softmax phase row ownership)
  const size_t grow0 = (size_t)blockIdx.x * 32;

  // B fragments for this wave: nt = wave*8 + nf, fragment (nf, kt) at
  // bb + (nf*32 + kt)*1024 bytes; lane's slice at +lane*16.
  const char* bb = (const char*)memTb + (size_t)(wave * 256) * 1024 + lane * 16;

  // --- 1. load this row's 1024 attn values across its 16 threads (64 each)
  f32x4 v[16];
  {
    const f32x4* arow = (const f32x4*)(attn + (grow0 + row) * 1024);
#pragma unroll
    for (int j = 0; j < 16; ++j) v[j] = arow[cg + j * 16];
  }

  // prefetch B-frags for kt=0 now; softmax waits on the attn loads with a
  // counted vmcnt, so these stay in flight under the math.
  half8 b0[8], b1[8];
#pragma unroll
  for (int nf = 0; nf < 8; ++nf)
    b0[nf] = *(const half8*)(bb + nf * 32768);

  // --- 2a. row max (reduce over the 16-lane row group)
  float m = -1e30f;
#pragma unroll
  for (int j = 0; j < 16; ++j)
    m = fmaxf(m, fmaxf(fmaxf(v[j].x, v[j].y), fmaxf(v[j].z, v[j].w)));
#pragma unroll
  for (int off = 1; off < 16; off <<= 1) m = fmaxf(m, __shfl_xor(m, off));

  // --- 2b. exp in place + row sum
  float s = 0.f;
#pragma unroll
  for (int j = 0; j < 16; ++j) {
    v[j].x = expf(v[j].x - m);
    v[j].y = expf(v[j].y - m);
    v[j].z = expf(v[j].z - m);
    v[j].w = expf(v[j].w - m);
    s += (v[j].x + v[j].y) + (v[j].z + v[j].w);
  }
#pragma unroll
  for (int off = 1; off < 16; off <<= 1) s += __shfl_xor(s, off);
  const float inv = 1.0f / s;

  // --- 3. write normalized fp16 probs to LDS, XOR-swizzled by row
  {
    const int swz = (row & 7) << 4;
    char* rbase = (char*)P + row * 2048;
#pragma unroll
    for (int j = 0; j < 16; ++j) {
      half4v o;
      o[0] = (_Float16)(v[j].x * inv);
      o[1] = (_Float16)(v[j].y * inv);
      o[2] = (_Float16)(v[j].z * inv);
      o[3] = (_Float16)(v[j].w * inv);
      const int byteoff = (cg * 8 + j * 128) ^ swz;   // 8B-aligned, bijective
      *(half4v*)(rbase + byteoff) = o;
    }
  }

  // prefetch B-frags for kt=1 before the barrier
#pragma unroll
  for (int nf = 0; nf < 8; ++nf)
    b1[nf] = *(const half8*)(bb + nf * 32768 + 1024);

  __syncthreads();

  // --- 4. context GEMM: out[32 rows][wave's 128 cols] = P @ mem
  // Depth-2 pipeline: step A consumes b0 (kt), step B consumes b1 (kt+1);
  // each step re-issues its buffer's loads for kt+2 after the MFMAs read it.
  const int fr = lane & 15;
  const int fko = (lane >> 4) * 8;   // k element offset within 32
  f32x4 acc[2][8] = {};

  for (int kt = 0; kt < 32; kt += 2) {
    // ---- step A: kt, uses b0
    {
      half8 a[2];
#pragma unroll
      for (int mf = 0; mf < 2; ++mf) {
        const int ar = mf * 16 + fr;
        const int kbyte = ((kt * 32 + fko) * 2) ^ ((ar & 7) << 4);
        a[mf] = *(const half8*)((const char*)P + ar * 2048 + kbyte);
      }
#pragma unroll
      for (int mf = 0; mf < 2; ++mf)
#pragma unroll
        for (int nf = 0; nf < 8; ++nf)
          acc[mf][nf] = __builtin_amdgcn_mfma_f32_16x16x32_f16(a[mf], b0[nf], acc[mf][nf], 0, 0, 0);
      if (kt + 2 < 32) {
#pragma unroll
        for (int nf = 0; nf < 8; ++nf)
          b0[nf] = *(const half8*)(bb + nf * 32768 + (kt + 2) * 1024);
      }
    }
    // ---- step B: kt+1, uses b1
    {
      half8 a[2];
#pragma unroll
      for (int mf = 0; mf < 2; ++mf) {
        const int ar = mf * 16 + fr;
        const int kbyte = (((kt + 1) * 32 + fko) * 2) ^ ((ar & 7) << 4);
        a[mf] = *(const half8*)((const char*)P + ar * 2048 + kbyte);
      }
#pragma unroll
      for (int mf = 0; mf < 2; ++mf)
#pragma unroll
        for (int nf = 0; nf < 8; ++nf)
          acc[mf][nf] = __builtin_amdgcn_mfma_f32_16x16x32_f16(a[mf], b1[nf], acc[mf][nf], 0, 0, 0);
      if (kt + 3 < 32) {
#pragma unroll
        for (int nf = 0; nf < 8; ++nf)
          b1[nf] = *(const half8*)(bb + nf * 32768 + (kt + 3) * 1024);
      }
    }
  }

  // --- epilogue. C/D layout: col = lane&15, row = (lane>>4)*4 + reg
  const int colbase = wave * 128;
  const int er = (lane >> 4) * 4;
  const int ec = lane & 15;
#pragma unroll
  for (int mf = 0; mf < 2; ++mf)
#pragma unroll
    for (int nf = 0; nf < 8; ++nf) {
      const int col = colbase + nf * 16 + ec;
#pragma unroll
      for (int r = 0; r < 4; ++r)
        out[(grow0 + mf * 16 + er + r) * 1024 + col] = acc[mf][nf][r];
    }
}

// ---------------------------------------------------------------------------
extern "C" void kernel_launch(void* const* d_in, const int* in_sizes, int n_in,
                              void* d_out, int out_size, void* d_ws, size_t ws_size,
                              hipStream_t stream) {
  const float* x   = (const float*)d_in[0];   // [32768][1024]
  const float* W   = (const float*)d_in[1];   // [1024][1024]  (out=e, in=d)
  const float* b   = (const float*)d_in[2];   // [1024]
  const float* mem = (const float*)d_in[3];   // [1024][1024]  (m, e)
  float* out = (float*)d_out;

  char* ws = (char*)d_ws;
  const size_t MB = 1024 * 1024;
  float*    attn  = (float*)(ws);              // 128 MB
  __bf16*   Mh    = (__bf16*)(ws + 192 * MB);  // 2 MB
  __bf16*   Ml    = (__bf16*)(ws + 194 * MB);  // 2 MB
  __bf16*   Wth   = (__bf16*)(ws + 196 * MB);  // 2 MB
  __bf16*   Wtl   = (__bf16*)(ws + 198 * MB);  // 2 MB
  __bf16*   Ph    = (__bf16*)(ws + 200 * MB);  // 2 MB
  __bf16*   Pl    = (__bf16*)(ws + 202 * MB);  // 2 MB
  _Float16* memTb = (_Float16*)(ws + 204 * MB);// 2 MB
  float*    cvec  = (float*)(ws + 206 * MB);   // 4 KB

  // preps (all tiny)
  split_mem<<<4096, 256, 0, stream>>>(mem, Mh, Ml);
  transpose_split_W<<<dim3(32, 32), dim3(32, 8), 0, stream>>>(W, Wth, Wtl);
  build_memTb<<<512, 256, 0, stream>>>(mem, memTb);
  bias_c<<<256, 256, 0, stream>>>(b, mem, cvec);

  // P = mem @ W  (P[m][d] = sum_e mem[m][e] W[e][d]); split-bf16, out split bf16
  gemm_split<0><<<dim3(8, 8), 256, 0, stream>>>(
      nullptr, Mh, Ml, Wth, Wtl, nullptr, Ph, Pl, nullptr);

  // attn = x @ P^T + c  (split-bf16 via inline x split; fp32 logits)
  gemm_split<1><<<dim3(8, 256), 256, 0, stream>>>(
      x, nullptr, nullptr, Ph, Pl, cvec, nullptr, nullptr, attn);

  // fused softmax + context = probs @ mem  (fragment-packed B, reg pipeline)
  fused_softmax_ctx<<<1024, 512, 0, stream>>>(attn, memTb, out);
}

// Round 6
// 591.743 us; speedup vs baseline: 1.2825x; 1.0140x over previous
//
#include <hip/hip_runtime.h>
#include <hip/hip_bf16.h>
#include <hip/hip_fp16.h>

// Problem dims (hard-coded): B=8, S=4096, DIM=1024, M=1024
// Algebraic restructure: attn = x @ (mem·W)^T + (mem·b); softmax; out = probs @ mem
// Round 6: the big attn GEMM ported to the 256x256 4-phase template
// (T2 LDS swizzle + T3/T4 phase pipeline with issue-early/drain-late vmcnt +
// T5 setprio). 3-product split-bf16 numerics bit-identical to round 5.
#define KDIM 1024

typedef __attribute__((ext_vector_type(8))) __bf16    bf16x8;
typedef __attribute__((ext_vector_type(4))) __bf16    bf16x4;
typedef __attribute__((ext_vector_type(8))) _Float16  half8;
typedef __attribute__((ext_vector_type(4))) _Float16  half4v;
typedef __attribute__((ext_vector_type(4))) float     f32x4;

// async global->LDS, 16B per lane. LDS base must be wave-uniform; HW adds lane*16.
__device__ __forceinline__ void g2l16(const void* g, void* l) {
  __builtin_amdgcn_global_load_lds(
      (const __attribute__((address_space(1))) unsigned int*)g,
      (__attribute__((address_space(3))) unsigned int*)l, 16, 0, 0);
}

__device__ __forceinline__ void split2(float v, __bf16& h, __bf16& l) {
  h = (__bf16)v;
  l = (__bf16)(v - (float)h);
}

// ---------------------------------------------------------------------------
// split mem into bf16 hi/lo (row-major [m][e], already B^T/A layout for P-GEMM)
__global__ __launch_bounds__(256) void split_mem(
    const float* __restrict__ mem, __bf16* __restrict__ Mh, __bf16* __restrict__ Ml) {
  int i = blockIdx.x * 256 + threadIdx.x;   // 1M threads
  __bf16 h, l;
  split2(mem[i], h, l);
  Mh[i] = h; Ml[i] = l;
}

// transpose W [e][d] -> Wt [d][e], split to bf16 hi/lo (B^T layout for P-GEMM)
__global__ __launch_bounds__(256) void transpose_split_W(
    const float* __restrict__ W, __bf16* __restrict__ Wth, __bf16* __restrict__ Wtl) {
  __shared__ float tl[32][33];
  int bx = blockIdx.x, by = blockIdx.y;
  int tx = threadIdx.x, ty = threadIdx.y;   // (32, 8)
#pragma unroll
  for (int j = 0; j < 4; ++j)
    tl[ty + 8 * j][tx] = W[(by * 32 + ty + 8 * j) * 1024 + bx * 32 + tx];
  __syncthreads();
#pragma unroll
  for (int j = 0; j < 4; ++j) {
    float v = tl[tx][ty + 8 * j];
    __bf16 h, l;
    split2(v, h, l);
    const int idx = (bx * 32 + ty + 8 * j) * 1024 + by * 32 + tx;
    Wth[idx] = h; Wtl[idx] = l;
  }
}

// mem [m][e] fp32 -> memTb fp16 packed in MFMA B-fragment lane order
// (see round-5 comment; unchanged)
__global__ __launch_bounds__(256) void build_memTb(
    const float* __restrict__ mem, _Float16* __restrict__ memTb) {
  const int id = blockIdx.x * 256 + threadIdx.x;   // 131072 threads
  const int l  = id & 63;
  const int f  = id >> 6;        // 0..2047
  const int kt = f & 31;
  const int nt = f >> 5;
  const int n  = nt * 16 + (l & 15);
  const int k0 = kt * 32 + (l >> 4) * 8;
  half8 o;
#pragma unroll
  for (int j = 0; j < 8; ++j)
    o[j] = (_Float16)mem[(size_t)(k0 + j) * 1024 + n];
  *(half8*)(memTb + (size_t)id * 8) = o;
}

// c[m] = sum_e b[e] * mem[m][e]  (fp32). One wave per row.
__global__ __launch_bounds__(256) void bias_c(
    const float* __restrict__ b, const float* __restrict__ mem,
    float* __restrict__ c) {
  const int wave = threadIdx.x >> 6, lane = threadIdx.x & 63;
  const int row = blockIdx.x * 4 + wave;
  float s = 0.f;
#pragma unroll
  for (int j = 0; j < 16; ++j) {
    const int e = lane + 64 * j;
    s += b[e] * mem[row * 1024 + e];
  }
#pragma unroll
  for (int off = 32; off; off >>= 1) s += __shfl_xor(s, off);
  if (lane == 0) c[row] = s;
}

// ---------------------------------------------------------------------------
// Split-bf16 compensated GEMM for the small P = mem @ W product (MODE 0 only
// now; 128x128 tile, known-good structure). Epilogue writes C as bf16 hi/lo.
__global__ __launch_bounds__(256) void gemm_p(
    const __bf16* __restrict__ Agh, const __bf16* __restrict__ Agl,
    const __bf16* __restrict__ Bgh, const __bf16* __restrict__ Bgl,
    __bf16* __restrict__ Oh, __bf16* __restrict__ Ol) {
  __shared__ __attribute__((aligned(16))) __bf16 Ah[128 * 32];
  __shared__ __attribute__((aligned(16))) __bf16 Al[128 * 32];
  __shared__ __attribute__((aligned(16))) __bf16 Bh[128 * 32];
  __shared__ __attribute__((aligned(16))) __bf16 Bl[128 * 32];

  const int t = threadIdx.x;
  const int wave = t >> 6;
  const int lane = t & 63;
  const int wm = wave & 1, wn = wave >> 1;

  const int nwg = gridDim.x * gridDim.y;
  int flat = blockIdx.y * gridDim.x + blockIdx.x;
  if ((nwg & 7) == 0) {
    const int cpx = nwg >> 3;
    flat = (flat & 7) * cpx + (flat >> 3);
  }
  const int tileN = (flat % gridDim.x) * 128;
  const int tileM = (flat / gridDim.x) * 128;

  f32x4 acc[4][4] = {};

  const int rS = lane >> 2;
  const int cS = (lane & 3) * 8;

  for (int kt = 0; kt < KDIM / 32; ++kt) {
    const int k0 = kt * 32;
    __syncthreads();
#pragma unroll
    for (int i = 0; i < 2; ++i) {
      const int rb = i * 64 + wave * 16;
      const int grb = (tileN + rb + rS) * KDIM + k0 + cS;
      g2l16(Bgh + grb, &Bh[rb * 32]);
      g2l16(Bgl + grb, &Bl[rb * 32]);
      const int gra = (tileM + rb + rS) * KDIM + k0 + cS;
      g2l16(Agh + gra, &Ah[rb * 32]);
      g2l16(Agl + gra, &Al[rb * 32]);
    }
    __syncthreads();

    const int fr = lane & 15;
    const int fk = (lane >> 4) * 8;
    bf16x8 afh[4], afl[4], bfh[4], bfl[4];
#pragma unroll
    for (int mf = 0; mf < 4; ++mf) {
      const int r = wm * 64 + mf * 16 + fr;
      afh[mf] = *(const bf16x8*)(&Ah[r * 32 + fk]);
      afl[mf] = *(const bf16x8*)(&Al[r * 32 + fk]);
    }
#pragma unroll
    for (int nf = 0; nf < 4; ++nf) {
      const int r = wn * 64 + nf * 16 + fr;
      bfh[nf] = *(const bf16x8*)(&Bh[r * 32 + fk]);
      bfl[nf] = *(const bf16x8*)(&Bl[r * 32 + fk]);
    }
#pragma unroll
    for (int mf = 0; mf < 4; ++mf)
#pragma unroll
      for (int nf = 0; nf < 4; ++nf) {
        acc[mf][nf] = __builtin_amdgcn_mfma_f32_16x16x32_bf16(afh[mf], bfh[nf], acc[mf][nf], 0, 0, 0);
        acc[mf][nf] = __builtin_amdgcn_mfma_f32_16x16x32_bf16(afh[mf], bfl[nf], acc[mf][nf], 0, 0, 0);
        acc[mf][nf] = __builtin_amdgcn_mfma_f32_16x16x32_bf16(afl[mf], bfh[nf], acc[mf][nf], 0, 0, 0);
      }
  }

  const int er = (lane >> 4) * 4;
  const int ec = lane & 15;
#pragma unroll
  for (int nf = 0; nf < 4; ++nf) {
    const int col = tileN + wn * 64 + nf * 16 + ec;
#pragma unroll
    for (int mf = 0; mf < 4; ++mf) {
#pragma unroll
      for (int r = 0; r < 4; ++r) {
        const int row = tileM + wm * 64 + mf * 16 + er + r;
        const size_t idx = (size_t)row * KDIM + col;
        float v = acc[mf][nf][r];
        __bf16 h = (__bf16)v;
        Oh[idx] = h;
        Ol[idx] = (__bf16)(v - (float)h);
      }
    }
  }
}

// ---------------------------------------------------------------------------
// attn = x @ P^T + c : 256x256 tile, BK=32, 8 waves, 4 quadrant-phases/K-tile.
// - A (x fp32): reg-staged (4 x f32x4/thread), split inline, ds_write with
//   T2 slot-swizzle (slot ^= (row>>1)&3) one K-tile ahead.
// - B (P hi/lo bf16): global_load_lds with pre-swizzled SOURCE column group
//   (linear LDS dest, swizzled read -> rule 21 satisfied).
// - Sync: raw s_barrier per phase; ONE hand-written vmcnt(0)+lgkmcnt(0) per
//   K-tile at P3-end, waiting only on ops issued >=2 phases earlier.
// - Numerics: same MFMA/fragging/order as round 5 -> bit-identical attn.
__global__ __launch_bounds__(512, 2) void gemm_attn_8ph(
    const float* __restrict__ X,
    const __bf16* __restrict__ Pgh, const __bf16* __restrict__ Pgl,
    const float* __restrict__ bias,
    float* __restrict__ Of) {
  // [2 buf][256 rows][32 k] bf16 each = 16 KB/buf; 4 arrays -> 128 KB total
  __shared__ __attribute__((aligned(16))) __bf16 AhL[2 * 8192];
  __shared__ __attribute__((aligned(16))) __bf16 AlL[2 * 8192];
  __shared__ __attribute__((aligned(16))) __bf16 BhL[2 * 8192];
  __shared__ __attribute__((aligned(16))) __bf16 BlL[2 * 8192];

  const int t = threadIdx.x;
  const int wave = t >> 6, lane = t & 63;
  const int wm = wave >> 2;        // 2 M-halves (128 rows each)
  const int wn = wave & 3;         // 4 N-quarters (64 cols each)

  // XCD-aware bijective remap; nwg = 4*128 = 512 (divisible by 8)
  int flat = blockIdx.y * 4 + blockIdx.x;
  flat = (flat & 7) * 64 + (flat >> 3);
  const int tileN = (flat & 3) * 256;
  const int tileM = (flat >> 2) * 256;

  // ---- staging geometry (per thread, hoisted)
  // B: flat16 = i*512 + t covers (row 0..255) x (16B slot 0..3)
  int rowB_[2], gsB_[2], ldsB_[2];
#pragma unroll
  for (int i = 0; i < 2; ++i) {
    const int f16 = i * 512 + t;
    rowB_[i] = f16 >> 2;
    const int slot = f16 & 3;
    gsB_[i] = slot ^ ((rowB_[i] >> 1) & 3);       // pre-swizzled src col group
    ldsB_[i] = (i * 512 + wave * 64) * 8;         // wave-uniform elem base
  }
  // A: flat4 = i*512 + t covers (row 0..255) x (8B col 0..7)
  int rowA_[4], colA_[4], physA_[4];
#pragma unroll
  for (int i = 0; i < 4; ++i) {
    const int f4 = i * 512 + t;
    rowA_[i] = f4 >> 3;
    const int col8 = f4 & 7;
    colA_[i] = col8 * 4;                           // fp32 element offset
    physA_[i] = rowA_[i] * 64 +
                ((((col8 >> 1) ^ ((rowA_[i] >> 1) & 3)) << 4)) + (col8 & 1) * 8;
  }

  // ---- fragment-read geometry
  const int fr = lane & 15;
  const int sc = lane >> 4;            // k col-group (16B slot)
  const int swF = (fr >> 1) & 3;       // row-dependent slot swizzle
  const int fragoff = ((sc ^ swF) << 4);

  f32x4 acc[8][4] = {};
  f32x4 xr[4];

  auto xload = [&](int k0) {
#pragma unroll
    for (int i = 0; i < 4; ++i)
      xr[i] = *(const f32x4*)(X + (size_t)(tileM + rowA_[i]) * 1024 + k0 + colA_[i]);
  };
  auto stageB = [&](int buf, int k0) {
#pragma unroll
    for (int i = 0; i < 2; ++i) {
      const size_t g = (size_t)(tileN + rowB_[i]) * 1024 + k0 + gsB_[i] * 8;
      g2l16(Pgh + g, &BhL[buf * 8192 + ldsB_[i]]);
      g2l16(Pgl + g, &BlL[buf * 8192 + ldsB_[i]]);
    }
  };
  auto xwrite = [&](int buf) {
#pragma unroll
    for (int i = 0; i < 4; ++i) {
      bf16x4 h, l;
#pragma unroll
      for (int j = 0; j < 4; ++j) {
        const float vj = xr[i][j];
        __bf16 hh = (__bf16)vj;
        h[j] = hh;
        l[j] = (__bf16)(vj - (float)hh);
      }
      *(bf16x4*)((char*)AhL + buf * 16384 + physA_[i]) = h;
      *(bf16x4*)((char*)AlL + buf * 16384 + physA_[i]) = l;
    }
  };
  auto mm3 = [&](f32x4& a, const bf16x8& ah, const bf16x8& al,
                 const bf16x8& bh, const bf16x8& bl) {
    a = __builtin_amdgcn_mfma_f32_16x16x32_bf16(ah, bh, a, 0, 0, 0);
    a = __builtin_amdgcn_mfma_f32_16x16x32_bf16(ah, bl, a, 0, 0, 0);
    a = __builtin_amdgcn_mfma_f32_16x16x32_bf16(al, bh, a, 0, 0, 0);
  };

  // ---- prologue: stage K-tile 0 into buffer 0
  xload(0);
  stageB(0, 0);
  xwrite(0);   // compiler emits counted vmcnt for xr before the splits
  asm volatile("s_waitcnt vmcnt(0) lgkmcnt(0)" ::: "memory");
  __builtin_amdgcn_s_barrier();

  int cur = 0;
  for (int kt = 0; kt < 32; ++kt) {
    const int nxt = cur ^ 1;
    const int k1 = (kt + 1) * 32;
    bf16x8 ah[4], al[4], b0h[2], b0l[2], b1h[2], b1l[2];

    // ---- P0: read A m0-3 + B n0-1; issue next-tile x loads + B g2l16
#pragma unroll
    for (int mf = 0; mf < 4; ++mf) {
      const int row = wm * 128 + mf * 16 + fr;
      const int off = cur * 16384 + row * 64 + fragoff;
      ah[mf] = *(const bf16x8*)((const char*)AhL + off);
      al[mf] = *(const bf16x8*)((const char*)AlL + off);
    }
#pragma unroll
    for (int nf = 0; nf < 2; ++nf) {
      const int row = wn * 64 + nf * 16 + fr;
      const int off = cur * 16384 + row * 64 + fragoff;
      b0h[nf] = *(const bf16x8*)((const char*)BhL + off);
      b0l[nf] = *(const bf16x8*)((const char*)BlL + off);
    }
    if (kt < 31) { xload(k1); stageB(nxt, k1); }
    __builtin_amdgcn_s_barrier();
    __builtin_amdgcn_s_setprio(1);
#pragma unroll
    for (int mf = 0; mf < 4; ++mf)
#pragma unroll
      for (int nf = 0; nf < 2; ++nf)
        mm3(acc[mf][nf], ah[mf], al[mf], b0h[nf], b0l[nf]);
    __builtin_amdgcn_s_setprio(0);
    __builtin_amdgcn_s_barrier();

    // ---- P1: read B n2-3; MFMA m0-3 x n2-3
#pragma unroll
    for (int nf = 0; nf < 2; ++nf) {
      const int row = wn * 64 + (2 + nf) * 16 + fr;
      const int off = cur * 16384 + row * 64 + fragoff;
      b1h[nf] = *(const bf16x8*)((const char*)BhL + off);
      b1l[nf] = *(const bf16x8*)((const char*)BlL + off);
    }
    __builtin_amdgcn_s_barrier();
    __builtin_amdgcn_s_setprio(1);
#pragma unroll
    for (int mf = 0; mf < 4; ++mf)
#pragma unroll
      for (int nf = 0; nf < 2; ++nf)
        mm3(acc[mf][2 + nf], ah[mf], al[mf], b1h[nf], b1l[nf]);
    __builtin_amdgcn_s_setprio(0);
    __builtin_amdgcn_s_barrier();

    // ---- P2: read A m4-7; split+write next-tile A; MFMA m4-7 x n0-1
#pragma unroll
    for (int mf = 0; mf < 4; ++mf) {
      const int row = wm * 128 + (4 + mf) * 16 + fr;
      const int off = cur * 16384 + row * 64 + fragoff;
      ah[mf] = *(const bf16x8*)((const char*)AhL + off);
      al[mf] = *(const bf16x8*)((const char*)AlL + off);
    }
    if (kt < 31) xwrite(nxt);   // auto vmcnt(4): waits x loads, B stays in flight
    __builtin_amdgcn_s_barrier();
    __builtin_amdgcn_s_setprio(1);
#pragma unroll
    for (int mf = 0; mf < 4; ++mf)
#pragma unroll
      for (int nf = 0; nf < 2; ++nf)
        mm3(acc[4 + mf][nf], ah[mf], al[mf], b0h[nf], b0l[nf]);
    __builtin_amdgcn_s_setprio(0);
    __builtin_amdgcn_s_barrier();

    // ---- P3: MFMA m4-7 x n2-3; tile-end drain (ops are >=2 phases old)
    __builtin_amdgcn_s_setprio(1);
#pragma unroll
    for (int mf = 0; mf < 4; ++mf)
#pragma unroll
      for (int nf = 0; nf < 2; ++nf)
        mm3(acc[4 + mf][2 + nf], ah[mf], al[mf], b1h[nf], b1l[nf]);
    __builtin_amdgcn_s_setprio(0);
    asm volatile("s_waitcnt vmcnt(0) lgkmcnt(0)" ::: "memory");
    __builtin_amdgcn_s_barrier();
    cur = nxt;
  }

  // ---- epilogue: C/D layout col = lane&15, row = (lane>>4)*4 + reg; + bias
  const int er = (lane >> 4) * 4;
  const int ec = lane & 15;
#pragma unroll
  for (int nf = 0; nf < 4; ++nf) {
    const int col = tileN + wn * 64 + nf * 16 + ec;
    const float bv = bias[col];
#pragma unroll
    for (int mf = 0; mf < 8; ++mf) {
#pragma unroll
      for (int r = 0; r < 4; ++r) {
        const int row = tileM + wm * 128 + mf * 16 + er + r;
        Of[(size_t)row * 1024 + col] = acc[mf][nf][r] + bv;
      }
    }
  }
}

// ---------------------------------------------------------------------------
// Fused softmax + context GEMM (unchanged from round 5: fragment-packed B,
// depth-2 register pipeline).
__global__ __launch_bounds__(512, 2) void fused_softmax_ctx(
    const float* __restrict__ attn, const _Float16* __restrict__ memTb,
    float* __restrict__ out) {
  __shared__ __attribute__((aligned(16))) _Float16 P[32 * 1024];  // 64 KB

  const int t = threadIdx.x;
  const int wave = t >> 6, lane = t & 63;
  const int riw = lane >> 4;
  const int cg = lane & 15;
  const int row = wave * 4 + riw;
  const size_t grow0 = (size_t)blockIdx.x * 32;

  const char* bb = (const char*)memTb + (size_t)(wave * 256) * 1024 + lane * 16;

  f32x4 v[16];
  {
    const f32x4* arow = (const f32x4*)(attn + (grow0 + row) * 1024);
#pragma unroll
    for (int j = 0; j < 16; ++j) v[j] = arow[cg + j * 16];
  }

  half8 b0[8], b1[8];
#pragma unroll
  for (int nf = 0; nf < 8; ++nf)
    b0[nf] = *(const half8*)(bb + nf * 32768);

  float m = -1e30f;
#pragma unroll
  for (int j = 0; j < 16; ++j)
    m = fmaxf(m, fmaxf(fmaxf(v[j].x, v[j].y), fmaxf(v[j].z, v[j].w)));
#pragma unroll
  for (int off = 1; off < 16; off <<= 1) m = fmaxf(m, __shfl_xor(m, off));

  float s = 0.f;
#pragma unroll
  for (int j = 0; j < 16; ++j) {
    v[j].x = expf(v[j].x - m);
    v[j].y = expf(v[j].y - m);
    v[j].z = expf(v[j].z - m);
    v[j].w = expf(v[j].w - m);
    s += (v[j].x + v[j].y) + (v[j].z + v[j].w);
  }
#pragma unroll
  for (int off = 1; off < 16; off <<= 1) s += __shfl_xor(s, off);
  const float inv = 1.0f / s;

  {
    const int swz = (row & 7) << 4;
    char* rbase = (char*)P + row * 2048;
#pragma unroll
    for (int j = 0; j < 16; ++j) {
      half4v o;
      o[0] = (_Float16)(v[j].x * inv);
      o[1] = (_Float16)(v[j].y * inv);
      o[2] = (_Float16)(v[j].z * inv);
      o[3] = (_Float16)(v[j].w * inv);
      const int byteoff = (cg * 8 + j * 128) ^ swz;
      *(half4v*)(rbase + byteoff) = o;
    }
  }

#pragma unroll
  for (int nf = 0; nf < 8; ++nf)
    b1[nf] = *(const half8*)(bb + nf * 32768 + 1024);

  __syncthreads();

  const int fr = lane & 15;
  const int fko = (lane >> 4) * 8;
  f32x4 acc[2][8] = {};

  for (int kt = 0; kt < 32; kt += 2) {
    {
      half8 a[2];
#pragma unroll
      for (int mf = 0; mf < 2; ++mf) {
        const int ar = mf * 16 + fr;
        const int kbyte = ((kt * 32 + fko) * 2) ^ ((ar & 7) << 4);
        a[mf] = *(const half8*)((const char*)P + ar * 2048 + kbyte);
      }
#pragma unroll
      for (int mf = 0; mf < 2; ++mf)
#pragma unroll
        for (int nf = 0; nf < 8; ++nf)
          acc[mf][nf] = __builtin_amdgcn_mfma_f32_16x16x32_f16(a[mf], b0[nf], acc[mf][nf], 0, 0, 0);
      if (kt + 2 < 32) {
#pragma unroll
        for (int nf = 0; nf < 8; ++nf)
          b0[nf] = *(const half8*)(bb + nf * 32768 + (kt + 2) * 1024);
      }
    }
    {
      half8 a[2];
#pragma unroll
      for (int mf = 0; mf < 2; ++mf) {
        const int ar = mf * 16 + fr;
        const int kbyte = (((kt + 1) * 32 + fko) * 2) ^ ((ar & 7) << 4);
        a[mf] = *(const half8*)((const char*)P + ar * 2048 + kbyte);
      }
#pragma unroll
      for (int mf = 0; mf < 2; ++mf)
#pragma unroll
        for (int nf = 0; nf < 8; ++nf)
          acc[mf][nf] = __builtin_amdgcn_mfma_f32_16x16x32_f16(a[mf], b1[nf], acc[mf][nf], 0, 0, 0);
      if (kt + 3 < 32) {
#pragma unroll
        for (int nf = 0; nf < 8; ++nf)
          b1[nf] = *(const half8*)(bb + nf * 32768 + (kt + 3) * 1024);
      }
    }
  }

  const int colbase = wave * 128;
  const int er = (lane >> 4) * 4;
  const int ec = lane & 15;
#pragma unroll
  for (int mf = 0; mf < 2; ++mf)
#pragma unroll
    for (int nf = 0; nf < 8; ++nf) {
      const int col = colbase + nf * 16 + ec;
#pragma unroll
      for (int r = 0; r < 4; ++r)
        out[(grow0 + mf * 16 + er + r) * 1024 + col] = acc[mf][nf][r];
    }
}

// ---------------------------------------------------------------------------
extern "C" void kernel_launch(void* const* d_in, const int* in_sizes, int n_in,
                              void* d_out, int out_size, void* d_ws, size_t ws_size,
                              hipStream_t stream) {
  const float* x   = (const float*)d_in[0];   // [32768][1024]
  const float* W   = (const float*)d_in[1];   // [1024][1024]  (out=e, in=d)
  const float* b   = (const float*)d_in[2];   // [1024]
  const float* mem = (const float*)d_in[3];   // [1024][1024]  (m, e)
  float* out = (float*)d_out;

  char* ws = (char*)d_ws;
  const size_t MB = 1024 * 1024;
  float*    attn  = (float*)(ws);              // 128 MB
  __bf16*   Mh    = (__bf16*)(ws + 192 * MB);  // 2 MB
  __bf16*   Ml    = (__bf16*)(ws + 194 * MB);  // 2 MB
  __bf16*   Wth   = (__bf16*)(ws + 196 * MB);  // 2 MB
  __bf16*   Wtl   = (__bf16*)(ws + 198 * MB);  // 2 MB
  __bf16*   Ph    = (__bf16*)(ws + 200 * MB);  // 2 MB
  __bf16*   Pl    = (__bf16*)(ws + 202 * MB);  // 2 MB
  _Float16* memTb = (_Float16*)(ws + 204 * MB);// 2 MB
  float*    cvec  = (float*)(ws + 206 * MB);   // 4 KB

  // preps (all tiny)
  split_mem<<<4096, 256, 0, stream>>>(mem, Mh, Ml);
  transpose_split_W<<<dim3(32, 32), dim3(32, 8), 0, stream>>>(W, Wth, Wtl);
  build_memTb<<<512, 256, 0, stream>>>(mem, memTb);
  bias_c<<<256, 256, 0, stream>>>(b, mem, cvec);

  // P = mem @ W  (split-bf16, out split bf16)
  gemm_p<<<dim3(8, 8), 256, 0, stream>>>(Mh, Ml, Wth, Wtl, Ph, Pl);

  // attn = x @ P^T + c  (256x256 4-phase pipelined split-bf16)
  gemm_attn_8ph<<<dim3(4, 128), 512, 0, stream>>>(x, Ph, Pl, cvec, attn);

  // fused softmax + context = probs @ mem  (fragment-packed B, reg pipeline)
  fused_softmax_ctx<<<1024, 512, 0, stream>>>(attn, memTb, out);
}